// Round 2
// baseline (712.559 us; speedup 1.0000x reference)
//
#include <hip/hip_runtime.h>
#include <hip/hip_bf16.h>

#define NN 50000
#define NE 800000
#define HD 128
#define NL 3
#define NG 512
#define LN_EPS 1e-5f

typedef unsigned short u16;
typedef unsigned int u32;
typedef __attribute__((ext_vector_type(8))) short short8;
typedef __attribute__((ext_vector_type(4))) float f32x4;

__device__ __forceinline__ u16 f2bf(float f){
  u32 x = __float_as_uint(f);
  u32 r = (x + 0x7fffu + ((x >> 16) & 1u)) >> 16;
  return (u16)r;
}

__device__ __forceinline__ int lower_bound_dev(const int* a, int n, int v){
  int lo = 0, hi = n;
  while (lo < hi){ int m = (lo + hi) >> 1; if (a[m] < v) lo = m + 1; else hi = m; }
  return lo;
}

// Wt[w][n][k] = bf16(W[k][n]); w = layer*2 + (0:W1, 1:W2)
__global__ __launch_bounds__(256) void k_prep_w(const float* __restrict__ W1,
    const float* __restrict__ W2, u16* __restrict__ Wt){
  int t = blockIdx.x * 256 + threadIdx.x;
  if (t >= 6 * 128 * 128) return;
  int w = t >> 14, r = t & 16383, n = r >> 7, k = r & 127;
  int l = w >> 1;
  const float* Ws = (w & 1) ? (W2 + l * 16384) : (W1 + l * 16384);
  Wt[t] = f2bf(Ws[k * 128 + n]);
}

__global__ __launch_bounds__(256) void k_embed(const int* __restrict__ z,
    const float* __restrict__ tab, float* __restrict__ x){
  int gt = blockIdx.x * 256 + threadIdx.x;   // exactly NN*32 threads
  int node = gt >> 5, q = gt & 31;
  float4 v = *reinterpret_cast<const float4*>(tab + (size_t)z[node] * 128 + q * 4);
  *reinterpret_cast<float4*>(x + (size_t)node * 128 + q * 4) = v;
}

__global__ __launch_bounds__(256) void k_count(const int* __restrict__ dst,
    int* __restrict__ deg){
  int e = blockIdx.x * 256 + threadIdx.x;
  if (e < NE) atomicAdd(&deg[dst[e]], 1);
}

__global__ __launch_bounds__(256) void k_scan1(const int* __restrict__ deg,
    int* __restrict__ part, int* __restrict__ bsum){
  int i = blockIdx.x * 256 + threadIdx.x;
  int v = (i < NN) ? deg[i] : 0;
  int lane = threadIdx.x & 63, wave = threadIdx.x >> 6;
  int s = v;
  for (int off = 1; off < 64; off <<= 1){ int n = __shfl_up(s, off); if (lane >= off) s += n; }
  __shared__ int wsums[4];
  if (lane == 63) wsums[wave] = s;
  __syncthreads();
  int add = 0;
  for (int w = 0; w < wave; ++w) add += wsums[w];
  int incl = s + add;
  if (i < NN) part[i] = incl - v;                 // exclusive within block
  if (threadIdx.x == 255) bsum[blockIdx.x] = incl; // block total
}

__global__ __launch_bounds__(256) void k_scan2(int* __restrict__ bsum, int nb){
  int tid = threadIdx.x;
  int v = (tid < nb) ? bsum[tid] : 0;
  int lane = tid & 63, wave = tid >> 6;
  int s = v;
  for (int off = 1; off < 64; off <<= 1){ int n = __shfl_up(s, off); if (lane >= off) s += n; }
  __shared__ int wsums[4];
  if (lane == 63) wsums[wave] = s;
  __syncthreads();
  int add = 0;
  for (int w = 0; w < wave; ++w) add += wsums[w];
  int incl = s + add;
  if (tid < nb) bsum[tid] = incl - v;
}

__global__ __launch_bounds__(256) void k_scan3(const int* __restrict__ part,
    const int* __restrict__ bsum, int* __restrict__ rowptr, int* __restrict__ cursor){
  int i = blockIdx.x * 256 + threadIdx.x;
  if (i < NN){ int r = part[i] + bsum[blockIdx.x]; rowptr[i] = r; cursor[i] = r; }
  if (i == 0) rowptr[NN] = NE;
}

__global__ __launch_bounds__(256) void k_fill(const int* __restrict__ src,
    const int* __restrict__ dst, int* __restrict__ cursor, int* __restrict__ col){
  int e = blockIdx.x * 256 + threadIdx.x;
  if (e < NE){ int p = atomicAdd(&cursor[dst[e]], 1); col[p] = src[e]; }
}

// h[n] = x[n] + sum_{e in CSR row n} x[col[e]]   (one wave per node)
__global__ __launch_bounds__(256) void k_gather(const int* __restrict__ rowptr,
    const int* __restrict__ col, const float* __restrict__ x, float* __restrict__ h){
  int wave = threadIdx.x >> 6, lane = threadIdx.x & 63;
  int node = blockIdx.x * 4 + wave;
  const float2* xp = reinterpret_cast<const float2*>(x);
  float2 acc = xp[(size_t)node * 64 + lane];
  int lo = rowptr[node], hi = rowptr[node + 1];
  for (int e = lo; e < hi; ++e){
    float2 v = xp[(size_t)col[e] * 64 + lane];
    acc.x += v.x; acc.y += v.y;
  }
  reinterpret_cast<float2*>(h)[(size_t)node * 64 + lane] = acc;
}

// C = relu(A @ W + bias), A fp32 [NN][128] staged to bf16 LDS (XOR-swizzled),
// Wt bf16 [n][k]. 128 rows/block, 4 waves x 32 rows, 16x16x32 MFMA.
__global__ __launch_bounds__(256) void k_gemm(const float* __restrict__ A,
    const u16* __restrict__ Wt, const float* __restrict__ bias, float* __restrict__ C){
  __shared__ u16 As[128 * 128];
  __shared__ u16 Bs[128 * 128];
  int tid = threadIdx.x;
  int rb = blockIdx.x * 128;

  // stage W: element (n,k) at n*128 + ((k/8)^(n&15))*8 + k%8
  for (int i = 0; i < 8; ++i){
    int u = tid + i * 256;            // 0..2047 chunks of 8 bf16
    int n = u >> 4, k8 = u & 15;
    uint4 w = *reinterpret_cast<const uint4*>(Wt + n * 128 + k8 * 8);
    int ch = k8 ^ (n & 15);
    *reinterpret_cast<uint4*>(&Bs[n * 128 + ch * 8]) = w;
  }
  // stage A (fp32 -> bf16, same swizzle)
  for (int i = 0; i < 16; ++i){
    int f4 = tid + i * 256;           // 0..4095 float4s
    int row = f4 >> 5, c4 = f4 & 31;
    int grow = rb + row;
    float4 v = {0.f, 0.f, 0.f, 0.f};
    if (grow < NN) v = *reinterpret_cast<const float4*>(A + (size_t)grow * 128 + c4 * 4);
    union { u16 u[4]; uint2 q; } pk;
    pk.u[0] = f2bf(v.x); pk.u[1] = f2bf(v.y); pk.u[2] = f2bf(v.z); pk.u[3] = f2bf(v.w);
    int ch = (c4 >> 1) ^ (row & 15);
    *reinterpret_cast<uint2*>(&As[row * 128 + ch * 8 + (c4 & 1) * 4]) = pk.q;
  }
  __syncthreads();

  int wave = tid >> 6, lane = tid & 63;
  int lrow = lane & 15, kgrp = lane >> 4;
  f32x4 acc[2][8];
  for (int rt = 0; rt < 2; ++rt)
    for (int nt = 0; nt < 8; ++nt) acc[rt][nt] = (f32x4){0.f, 0.f, 0.f, 0.f};

  for (int ks = 0; ks < 4; ++ks){
    int ch = ks * 4 + kgrp;
    short8 a0 = *reinterpret_cast<const short8*>(&As[(wave * 32 + lrow) * 128 + (ch ^ lrow) * 8]);
    short8 a1 = *reinterpret_cast<const short8*>(&As[(wave * 32 + 16 + lrow) * 128 + (ch ^ lrow) * 8]);
    for (int nt = 0; nt < 8; ++nt){
      short8 b = *reinterpret_cast<const short8*>(&Bs[(nt * 16 + lrow) * 128 + (ch ^ lrow) * 8]);
      acc[0][nt] = __builtin_amdgcn_mfma_f32_16x16x32_bf16(a0, b, acc[0][nt], 0, 0, 0);
      acc[1][nt] = __builtin_amdgcn_mfma_f32_16x16x32_bf16(a1, b, acc[1][nt], 0, 0, 0);
    }
  }

  for (int nt = 0; nt < 8; ++nt){
    int gcol = nt * 16 + lrow;
    float bv = __ldg(bias + gcol);
    for (int rt = 0; rt < 2; ++rt){
      int rbase = rb + wave * 32 + rt * 16 + kgrp * 4;
      for (int j = 0; j < 4; ++j){
        int grow = rbase + j;
        if (grow < NN){
          float val = acc[rt][nt][j] + bv;
          C[(size_t)grow * 128 + gcol] = fmaxf(val, 0.f);
        }
      }
    }
  }
}

__global__ __launch_bounds__(256) void k_ln(const float* __restrict__ hin,
    const float* __restrict__ g, const float* __restrict__ b, float* __restrict__ xo){
  int wave = threadIdx.x >> 6, lane = threadIdx.x & 63;
  int node = blockIdx.x * 4 + wave;
  float2 v = *reinterpret_cast<const float2*>(hin + (size_t)node * 128 + lane * 2);
  float s = v.x + v.y, sq = v.x * v.x + v.y * v.y;
  for (int off = 32; off; off >>= 1){ s += __shfl_xor(s, off); sq += __shfl_xor(sq, off); }
  float mu = s * (1.f / 128.f);
  float var = sq * (1.f / 128.f) - mu * mu;
  float rstd = rsqrtf(var + LN_EPS);
  float2 gg = *reinterpret_cast<const float2*>(g + lane * 2);
  float2 bb = *reinterpret_cast<const float2*>(b + lane * 2);
  float2 y = { gg.x * (v.x - mu) * rstd + bb.x, gg.y * (v.y - mu) * rstd + bb.y };
  *reinterpret_cast<float2*>(xo + (size_t)node * 128 + lane * 2) = y;
}

// per-graph sums of one layer slice into pooled[g][384]
__global__ __launch_bounds__(128) void k_pool(const float* __restrict__ x,
    const int* __restrict__ batch, float* __restrict__ pooled, int lslice){
  int g = blockIdx.x, f = threadIdx.x;
  int lo = lower_bound_dev(batch, NN, g);
  int hi = lower_bound_dev(batch, NN, g + 1);
  float s = 0.f;
  for (int i = lo; i < hi; ++i) s += x[(size_t)i * 128 + f];
  pooled[(size_t)g * 384 + lslice * 128 + f] = s;
}

__global__ __launch_bounds__(128) void k_final(const float* __restrict__ pooled,
    const int* __restrict__ batch, const float* __restrict__ W1,
    const float* __restrict__ b1, const float* __restrict__ W2,
    const float* __restrict__ b2, float* __restrict__ out){
  int g = blockIdx.x, f = threadIdx.x;
  int lo = lower_bound_dev(batch, NN, g);
  int hi = lower_bound_dev(batch, NN, g + 1);
  float scale = 1.f / fmaxf((float)(hi - lo), 1.f);
  __shared__ float p[384];
  for (int k = f; k < 384; k += 128) p[k] = pooled[(size_t)g * 384 + k] * scale;
  __syncthreads();
  float acc = __ldg(b1 + f);
  for (int k = 0; k < 384; ++k) acc += p[k] * __ldg(W1 + k * 128 + f);
  float hval = fmaxf(acc, 0.f);
  float v = hval * __ldg(W2 + f);
  for (int off = 32; off; off >>= 1) v += __shfl_xor(v, off);
  __shared__ float red[2];
  int lane = f & 63, wave = f >> 6;
  if (lane == 0) red[wave] = v;
  __syncthreads();
  if (f == 0) out[g] = red[0] + red[1] + __ldg(b2);
}

extern "C" void kernel_launch(void* const* d_in, const int* in_sizes, int n_in,
                              void* d_out, int out_size, void* d_ws, size_t ws_size,
                              hipStream_t stream){
  const int*   z     = (const int*)d_in[0];
  const int*   ei    = (const int*)d_in[1];
  const int*   batch = (const int*)d_in[2];
  const float* ztab  = (const float*)d_in[3];
  const float* W1    = (const float*)d_in[4];
  const float* b1    = (const float*)d_in[5];
  const float* W2    = (const float*)d_in[6];
  const float* b2    = (const float*)d_in[7];
  const float* lng   = (const float*)d_in[8];
  const float* lnb   = (const float*)d_in[9];
  const float* l1W   = (const float*)d_in[10];
  const float* l1b   = (const float*)d_in[11];
  const float* l2W   = (const float*)d_in[12];
  const float* l2b   = (const float*)d_in[13];
  float* out = (float*)d_out;

  char* wsb = (char*)d_ws;
  size_t off = 0;
  auto alloc = [&](size_t bytes){ void* p = wsb + off; off += (bytes + 255) & ~(size_t)255; return p; };
  float* x      = (float*)alloc((size_t)NN * 128 * 4);
  float* h      = (float*)alloc((size_t)NN * 128 * 4);
  float* h2     = (float*)alloc((size_t)NN * 128 * 4);
  float* pooled = (float*)alloc((size_t)NG * 384 * 4);
  u16*   Wt     = (u16*)alloc((size_t)6 * 128 * 128 * 2);
  int*   deg    = (int*)alloc((size_t)NN * 4);
  int*   part   = (int*)alloc((size_t)NN * 4);
  int*   bsum   = (int*)alloc((size_t)256 * 4);
  int*   rowptr = (int*)alloc((size_t)(NN + 1) * 4);
  int*   cursor = (int*)alloc((size_t)NN * 4);
  int*   col    = (int*)alloc((size_t)NE * 4);

  const int* srcv = ei;
  const int* dstv = ei + NE;

  hipMemsetAsync(deg, 0, (size_t)NN * 4, stream);
  k_prep_w<<<(6 * 128 * 128 + 255) / 256, 256, 0, stream>>>(W1, W2, Wt);
  k_embed<<<NN * 32 / 256, 256, 0, stream>>>(z, ztab, x);
  k_count<<<(NE + 255) / 256, 256, 0, stream>>>(dstv, deg);
  int nb = (NN + 255) / 256;  // 196
  k_scan1<<<nb, 256, 0, stream>>>(deg, part, bsum);
  k_scan2<<<1, 256, 0, stream>>>(bsum, nb);
  k_scan3<<<nb, 256, 0, stream>>>(part, bsum, rowptr, cursor);
  k_fill<<<(NE + 255) / 256, 256, 0, stream>>>(srcv, dstv, cursor, col);

  for (int l = 0; l < NL; ++l){
    k_gather<<<NN / 4, 256, 0, stream>>>(rowptr, col, x, h);
    k_gemm<<<(NN + 127) / 128, 256, 0, stream>>>(h,  Wt + (size_t)(l * 2 + 0) * 16384, b1 + l * 128, h2);
    k_gemm<<<(NN + 127) / 128, 256, 0, stream>>>(h2, Wt + (size_t)(l * 2 + 1) * 16384, b2 + l * 128, h2);
    k_ln<<<NN / 4, 256, 0, stream>>>(h2, lng + l * 128, lnb + l * 128, x);
    k_pool<<<NG, 128, 0, stream>>>(x, batch, pooled, l);
  }
  k_final<<<NG, 128, 0, stream>>>(pooled, batch, l1W, l1b, l2W, l2b, out);
}

// Round 3
// 467.822 us; speedup vs baseline: 1.5231x; 1.5231x over previous
//
#include <hip/hip_runtime.h>
#include <hip/hip_bf16.h>

#define NN 50000
#define NE 800000
#define HD 128
#define NL 3
#define NG 512
#define LN_EPS 1e-5f

typedef unsigned short u16;
typedef unsigned int u32;
typedef __attribute__((ext_vector_type(8))) short short8;
typedef __attribute__((ext_vector_type(4))) float f32x4;

__device__ __forceinline__ u16 f2bf(float f){
  u32 x = __float_as_uint(f);
  u32 r = (x + 0x7fffu + ((x >> 16) & 1u)) >> 16;
  return (u16)r;
}
__device__ __forceinline__ float blo(u32 u){ return __uint_as_float(u << 16); }
__device__ __forceinline__ float bhi(u32 u){ return __uint_as_float(u & 0xffff0000u); }
__device__ __forceinline__ u32 pk2(float a, float b){ return (u32)f2bf(a) | ((u32)f2bf(b) << 16); }

__device__ __forceinline__ int lower_bound_dev(const int* a, int n, int v){
  int lo = 0, hi = n;
  while (lo < hi){ int m = (lo + hi) >> 1; if (a[m] < v) lo = m + 1; else hi = m; }
  return lo;
}

// Wt[w][n][k] = bf16(W[k][n]); w = layer*2 + (0:W1, 1:W2)
__global__ __launch_bounds__(256) void k_prep_w(const float* __restrict__ W1,
    const float* __restrict__ W2, u16* __restrict__ Wt){
  int t = blockIdx.x * 256 + threadIdx.x;
  if (t >= 6 * 128 * 128) return;
  int w = t >> 14, r = t & 16383, n = r >> 7, k = r & 127;
  int l = w >> 1;
  const float* Ws = (w & 1) ? (W2 + l * 16384) : (W1 + l * 16384);
  Wt[t] = f2bf(Ws[k * 128 + n]);
}

__global__ __launch_bounds__(256) void k_embed(const int* __restrict__ z,
    const float* __restrict__ tab, u16* __restrict__ xb){
  int gt = blockIdx.x * 256 + threadIdx.x;   // NN*32 threads, 4 floats each
  int node = gt >> 5, q = gt & 31;
  float4 v = *reinterpret_cast<const float4*>(tab + (size_t)z[node] * 128 + q * 4);
  uint2 p = { pk2(v.x, v.y), pk2(v.z, v.w) };
  *reinterpret_cast<uint2*>(xb + (size_t)node * 128 + q * 4) = p;
}

__global__ __launch_bounds__(256) void k_count(const int* __restrict__ dst,
    int* __restrict__ deg){
  int e = blockIdx.x * 256 + threadIdx.x;
  if (e < NE) atomicAdd(&deg[dst[e]], 1);
}

__global__ __launch_bounds__(256) void k_scan1(const int* __restrict__ deg,
    int* __restrict__ part, int* __restrict__ bsum){
  int i = blockIdx.x * 256 + threadIdx.x;
  int v = (i < NN) ? deg[i] : 0;
  int lane = threadIdx.x & 63, wave = threadIdx.x >> 6;
  int s = v;
  for (int off = 1; off < 64; off <<= 1){ int n = __shfl_up(s, off); if (lane >= off) s += n; }
  __shared__ int wsums[4];
  if (lane == 63) wsums[wave] = s;
  __syncthreads();
  int add = 0;
  for (int w = 0; w < wave; ++w) add += wsums[w];
  int incl = s + add;
  if (i < NN) part[i] = incl - v;
  if (threadIdx.x == 255) bsum[blockIdx.x] = incl;
}

__global__ __launch_bounds__(256) void k_scan2(int* __restrict__ bsum, int nb){
  int tid = threadIdx.x;
  int v = (tid < nb) ? bsum[tid] : 0;
  int lane = tid & 63, wave = tid >> 6;
  int s = v;
  for (int off = 1; off < 64; off <<= 1){ int n = __shfl_up(s, off); if (lane >= off) s += n; }
  __shared__ int wsums[4];
  if (lane == 63) wsums[wave] = s;
  __syncthreads();
  int add = 0;
  for (int w = 0; w < wave; ++w) add += wsums[w];
  int incl = s + add;
  if (tid < nb) bsum[tid] = incl - v;
}

__global__ __launch_bounds__(256) void k_scan3(const int* __restrict__ part,
    const int* __restrict__ bsum, int* __restrict__ rowptr, int* __restrict__ cursor){
  int i = blockIdx.x * 256 + threadIdx.x;
  if (i < NN){ int r = part[i] + bsum[blockIdx.x]; rowptr[i] = r; cursor[i] = r; }
  if (i == 0) rowptr[NN] = NE;
}

__global__ __launch_bounds__(256) void k_fill(const int* __restrict__ src,
    const int* __restrict__ dst, int* __restrict__ cursor, int* __restrict__ col){
  int e = blockIdx.x * 256 + threadIdx.x;
  if (e < NE){ int p = atomicAdd(&cursor[dst[e]], 1); col[p] = src[e]; }
}

// h[n] = x[n] + sum neighbors, bf16 in/out, 2 edges per wave-iteration.
__global__ __launch_bounds__(256) void k_gather(const int* __restrict__ rowptr,
    const int* __restrict__ col, const u16* __restrict__ xb, u16* __restrict__ hb){
  int wave = threadIdx.x >> 6, lane = threadIdx.x & 63;
  int node = blockIdx.x * 4 + wave;
  int half = lane >> 5, l5 = lane & 31;
  float a0 = 0.f, a1 = 0.f, a2 = 0.f, a3 = 0.f;
  if (half == 0){
    uint2 s = *reinterpret_cast<const uint2*>(xb + (size_t)node * 128 + l5 * 4);
    a0 = blo(s.x); a1 = bhi(s.x); a2 = blo(s.y); a3 = bhi(s.y);
  }
  int lo = rowptr[node], hi = rowptr[node + 1];
  for (int e = lo + half; e < hi; e += 2){
    int c = col[e];
    uint2 v = *reinterpret_cast<const uint2*>(xb + (size_t)c * 128 + l5 * 4);
    a0 += blo(v.x); a1 += bhi(v.x); a2 += blo(v.y); a3 += bhi(v.y);
  }
  a0 += __shfl_xor(a0, 32); a1 += __shfl_xor(a1, 32);
  a2 += __shfl_xor(a2, 32); a3 += __shfl_xor(a3, 32);
  if (half == 0){
    uint2 p = { pk2(a0, a1), pk2(a2, a3) };
    *reinterpret_cast<uint2*>(hb + (size_t)node * 128 + l5 * 4) = p;
  }
}

// C = relu(A @ W + bias) [+ LayerNorm if DO_LN], bf16 in, bf16 out.
// 128 rows/block, 4 waves, 16x16x32 MFMA, XOR-swizzled LDS tiles.
template<int DO_LN>
__global__ __launch_bounds__(256) void k_gemm_f(const u16* __restrict__ A,
    const u16* __restrict__ Wt, const float* __restrict__ bias,
    const float* __restrict__ lng, const float* __restrict__ lnb,
    u16* __restrict__ Cout){
  __shared__ u16 As[128 * 128];
  __shared__ u16 Bs[128 * 128];
  int tid = threadIdx.x;
  int rb = blockIdx.x * 128;

  #pragma unroll
  for (int i = 0; i < 8; ++i){
    int u = tid + i * 256;            // 0..2047 chunks of 8 bf16
    int n = u >> 4, k8 = u & 15;
    uint4 w = *reinterpret_cast<const uint4*>(Wt + n * 128 + k8 * 8);
    *reinterpret_cast<uint4*>(&Bs[n * 128 + (k8 ^ (n & 15)) * 8]) = w;
  }
  #pragma unroll
  for (int i = 0; i < 8; ++i){
    int u = tid + i * 256;
    int row = u >> 4, k8 = u & 15;
    int grow = rb + row;
    uint4 v = {0u, 0u, 0u, 0u};
    if (grow < NN) v = *reinterpret_cast<const uint4*>(A + (size_t)grow * 128 + k8 * 8);
    *reinterpret_cast<uint4*>(&As[row * 128 + (k8 ^ (row & 15)) * 8]) = v;
  }
  __syncthreads();

  int wave = tid >> 6, lane = tid & 63;
  int lrow = lane & 15, kgrp = lane >> 4;
  f32x4 acc[2][8];
  #pragma unroll
  for (int rt = 0; rt < 2; ++rt)
    #pragma unroll
    for (int nt = 0; nt < 8; ++nt) acc[rt][nt] = (f32x4){0.f, 0.f, 0.f, 0.f};

  #pragma unroll
  for (int ks = 0; ks < 4; ++ks){
    int ch = ks * 4 + kgrp;
    short8 a0 = *reinterpret_cast<const short8*>(&As[(wave * 32 + lrow) * 128 + (ch ^ lrow) * 8]);
    short8 a1 = *reinterpret_cast<const short8*>(&As[(wave * 32 + 16 + lrow) * 128 + (ch ^ lrow) * 8]);
    #pragma unroll
    for (int nt = 0; nt < 8; ++nt){
      short8 b = *reinterpret_cast<const short8*>(&Bs[(nt * 16 + lrow) * 128 + (ch ^ lrow) * 8]);
      acc[0][nt] = __builtin_amdgcn_mfma_f32_16x16x32_bf16(a0, b, acc[0][nt], 0, 0, 0);
      acc[1][nt] = __builtin_amdgcn_mfma_f32_16x16x32_bf16(a1, b, acc[1][nt], 0, 0, 0);
    }
  }

  // epilogue: bias + relu (+ LN), all in registers
  float bv[8], gv[8], lbv[8];
  #pragma unroll
  for (int nt = 0; nt < 8; ++nt){
    int gcol = nt * 16 + lrow;
    bv[nt] = __ldg(bias + gcol);
    if (DO_LN){ gv[nt] = __ldg(lng + gcol); lbv[nt] = __ldg(lnb + gcol); }
  }
  #pragma unroll
  for (int rt = 0; rt < 2; ++rt)
    #pragma unroll
    for (int nt = 0; nt < 8; ++nt)
      #pragma unroll
      for (int j = 0; j < 4; ++j)
        acc[rt][nt][j] = fmaxf(acc[rt][nt][j] + bv[nt], 0.f);

  if (DO_LN){
    // row r = wave*32 + rt*16 + kgrp*4 + j; its 128 cols live in the 16 lanes
    // sharing (kgrp) at this (rt,j), 8 regs (nt) each. Reduce over nt + lrow.
    #pragma unroll
    for (int rt = 0; rt < 2; ++rt)
      #pragma unroll
      for (int j = 0; j < 4; ++j){
        float s = 0.f, sq = 0.f;
        #pragma unroll
        for (int nt = 0; nt < 8; ++nt){ float v = acc[rt][nt][j]; s += v; sq += v * v; }
        #pragma unroll
        for (int off = 1; off < 16; off <<= 1){
          s += __shfl_xor(s, off); sq += __shfl_xor(sq, off);
        }
        float mu = s * (1.f / 128.f);
        float var = sq * (1.f / 128.f) - mu * mu;
        float rstd = rsqrtf(var + LN_EPS);
        #pragma unroll
        for (int nt = 0; nt < 8; ++nt)
          acc[rt][nt][j] = gv[nt] * (acc[rt][nt][j] - mu) * rstd + lbv[nt];
      }
  }

  #pragma unroll
  for (int rt = 0; rt < 2; ++rt){
    int rbase = rb + wave * 32 + rt * 16 + kgrp * 4;
    #pragma unroll
    for (int nt = 0; nt < 8; ++nt){
      int gcol = nt * 16 + lrow;
      #pragma unroll
      for (int j = 0; j < 4; ++j){
        int grow = rbase + j;
        if (grow < NN) Cout[(size_t)grow * 128 + gcol] = f2bf(acc[rt][nt][j]);
      }
    }
  }
}

// per-graph sums of one layer slice into pooled[g][384]; 4 waves stride nodes
__global__ __launch_bounds__(256) void k_pool(const u16* __restrict__ xb,
    const int* __restrict__ batch, float* __restrict__ pooled, int lslice){
  int g = blockIdx.x;
  int w = threadIdx.x >> 6, lane = threadIdx.x & 63;
  __shared__ float red[4][128];
  int lo = lower_bound_dev(batch, NN, g);
  int hi = lower_bound_dev(batch, NN, g + 1);
  float s0 = 0.f, s1 = 0.f;
  for (int i = lo + w; i < hi; i += 4){
    u32 u = *reinterpret_cast<const u32*>(xb + (size_t)i * 128 + lane * 2);
    s0 += blo(u); s1 += bhi(u);
  }
  red[w][lane * 2] = s0; red[w][lane * 2 + 1] = s1;
  __syncthreads();
  int f = threadIdx.x;
  if (f < 128)
    pooled[(size_t)g * 384 + lslice * 128 + f] = red[0][f] + red[1][f] + red[2][f] + red[3][f];
}

__global__ __launch_bounds__(128) void k_final(const float* __restrict__ pooled,
    const int* __restrict__ batch, const float* __restrict__ W1,
    const float* __restrict__ b1, const float* __restrict__ W2,
    const float* __restrict__ b2, float* __restrict__ out){
  int g = blockIdx.x, f = threadIdx.x;
  int lo = lower_bound_dev(batch, NN, g);
  int hi = lower_bound_dev(batch, NN, g + 1);
  float scale = 1.f / fmaxf((float)(hi - lo), 1.f);
  __shared__ float p[384];
  for (int k = f; k < 384; k += 128) p[k] = pooled[(size_t)g * 384 + k] * scale;
  __syncthreads();
  float acc = __ldg(b1 + f);
  for (int k = 0; k < 384; ++k) acc += p[k] * __ldg(W1 + k * 128 + f);
  float hval = fmaxf(acc, 0.f);
  float v = hval * __ldg(W2 + f);
  for (int off = 32; off; off >>= 1) v += __shfl_xor(v, off);
  __shared__ float red[2];
  int lane = f & 63, wave = f >> 6;
  if (lane == 0) red[wave] = v;
  __syncthreads();
  if (f == 0) out[g] = red[0] + red[1] + __ldg(b2);
}

extern "C" void kernel_launch(void* const* d_in, const int* in_sizes, int n_in,
                              void* d_out, int out_size, void* d_ws, size_t ws_size,
                              hipStream_t stream){
  const int*   z     = (const int*)d_in[0];
  const int*   ei    = (const int*)d_in[1];
  const int*   batch = (const int*)d_in[2];
  const float* ztab  = (const float*)d_in[3];
  const float* W1    = (const float*)d_in[4];
  const float* b1    = (const float*)d_in[5];
  const float* W2    = (const float*)d_in[6];
  const float* b2    = (const float*)d_in[7];
  const float* lng   = (const float*)d_in[8];
  const float* lnb   = (const float*)d_in[9];
  const float* l1W   = (const float*)d_in[10];
  const float* l1b   = (const float*)d_in[11];
  const float* l2W   = (const float*)d_in[12];
  const float* l2b   = (const float*)d_in[13];
  float* out = (float*)d_out;

  char* wsb = (char*)d_ws;
  size_t off = 0;
  auto alloc = [&](size_t bytes){ void* p = wsb + off; off += (bytes + 255) & ~(size_t)255; return p; };
  u16*   xbf    = (u16*)alloc((size_t)NN * 128 * 2);
  u16*   hbf    = (u16*)alloc((size_t)NN * 128 * 2);
  u16*   h1bf   = (u16*)alloc((size_t)NN * 128 * 2);
  float* pooled = (float*)alloc((size_t)NG * 384 * 4);
  u16*   Wt     = (u16*)alloc((size_t)6 * 128 * 128 * 2);
  int*   deg    = (int*)alloc((size_t)NN * 4);
  int*   part   = (int*)alloc((size_t)NN * 4);
  int*   bsum   = (int*)alloc((size_t)256 * 4);
  int*   rowptr = (int*)alloc((size_t)(NN + 1) * 4);
  int*   cursor = (int*)alloc((size_t)NN * 4);
  int*   col    = (int*)alloc((size_t)NE * 4);

  const int* srcv = ei;
  const int* dstv = ei + NE;

  hipMemsetAsync(deg, 0, (size_t)NN * 4, stream);
  k_prep_w<<<(6 * 128 * 128 + 255) / 256, 256, 0, stream>>>(W1, W2, Wt);
  k_embed<<<NN * 32 / 256, 256, 0, stream>>>(z, ztab, xbf);
  k_count<<<(NE + 255) / 256, 256, 0, stream>>>(dstv, deg);
  int nb = (NN + 255) / 256;  // 196
  k_scan1<<<nb, 256, 0, stream>>>(deg, part, bsum);
  k_scan2<<<1, 256, 0, stream>>>(bsum, nb);
  k_scan3<<<nb, 256, 0, stream>>>(part, bsum, rowptr, cursor);
  k_fill<<<(NE + 255) / 256, 256, 0, stream>>>(srcv, dstv, cursor, col);

  int gb = (NN + 127) / 128;  // 391
  for (int l = 0; l < NL; ++l){
    k_gather<<<NN / 4, 256, 0, stream>>>(rowptr, col, xbf, hbf);
    k_gemm_f<0><<<gb, 256, 0, stream>>>(hbf,  Wt + (size_t)(l * 2 + 0) * 16384,
                                        b1 + l * 128, nullptr, nullptr, h1bf);
    k_gemm_f<1><<<gb, 256, 0, stream>>>(h1bf, Wt + (size_t)(l * 2 + 1) * 16384,
                                        b2 + l * 128, lng + l * 128, lnb + l * 128, xbf);
    k_pool<<<NG, 256, 0, stream>>>(xbf, batch, pooled, l);
  }
  k_final<<<NG, 128, 0, stream>>>(pooled, batch, l1W, l1b, l2W, l2b, out);
}

// Round 5
// 424.498 us; speedup vs baseline: 1.6786x; 1.1021x over previous
//
#include <hip/hip_runtime.h>
#include <hip/hip_bf16.h>

#define NN 50000
#define NE 800000
#define HD 128
#define NL 3
#define NG 512
#define LN_EPS 1e-5f

typedef unsigned short u16;
typedef unsigned int u32;
typedef __attribute__((ext_vector_type(8))) short short8;
typedef __attribute__((ext_vector_type(4))) float f32x4;

__device__ __forceinline__ u16 f2bf(float f){
  u32 x = __float_as_uint(f);
  u32 r = (x + 0x7fffu + ((x >> 16) & 1u)) >> 16;
  return (u16)r;
}
__device__ __forceinline__ float blo(u32 u){ return __uint_as_float(u << 16); }
__device__ __forceinline__ float bhi(u32 u){ return __uint_as_float(u & 0xffff0000u); }
__device__ __forceinline__ u32 pk2(float a, float b){ return (u32)f2bf(a) | ((u32)f2bf(b) << 16); }

__device__ __forceinline__ int lower_bound_dev(const int* a, int n, int v){
  int lo = 0, hi = n;
  while (lo < hi){ int m = (lo + hi) >> 1; if (a[m] < v) lo = m + 1; else hi = m; }
  return lo;
}

// Wt[w][n][k] = bf16(W[k][n]); w = layer*2 + (0:W1, 1:W2)
__global__ __launch_bounds__(256) void k_prep_w(const float* __restrict__ W1,
    const float* __restrict__ W2, u16* __restrict__ Wt){
  int t = blockIdx.x * 256 + threadIdx.x;
  if (t >= 6 * 128 * 128) return;
  int w = t >> 14, r = t & 16383, n = r >> 7, k = r & 127;
  int l = w >> 1;
  const float* Ws = (w & 1) ? (W2 + l * 16384) : (W1 + l * 16384);
  Wt[t] = f2bf(Ws[k * 128 + n]);
}

__global__ __launch_bounds__(256) void k_embed(const int* __restrict__ z,
    const float* __restrict__ tab, u16* __restrict__ xb){
  int gt = blockIdx.x * 256 + threadIdx.x;   // NN*32 threads, 4 floats each
  int node = gt >> 5, q = gt & 31;
  float4 v = *reinterpret_cast<const float4*>(tab + (size_t)z[node] * 128 + q * 4);
  uint2 p = { pk2(v.x, v.y), pk2(v.z, v.w) };
  *reinterpret_cast<uint2*>(xb + (size_t)node * 128 + q * 4) = p;
}

__global__ __launch_bounds__(256) void k_count(const int* __restrict__ dst,
    int* __restrict__ deg){
  int e = blockIdx.x * 256 + threadIdx.x;
  if (e < NE) atomicAdd(&deg[dst[e]], 1);
}

__global__ __launch_bounds__(256) void k_scan1(const int* __restrict__ deg,
    int* __restrict__ part, int* __restrict__ bsum){
  int i = blockIdx.x * 256 + threadIdx.x;
  int v = (i < NN) ? deg[i] : 0;
  int lane = threadIdx.x & 63, wave = threadIdx.x >> 6;
  int s = v;
  for (int off = 1; off < 64; off <<= 1){ int n = __shfl_up(s, off); if (lane >= off) s += n; }
  __shared__ int wsums[4];
  if (lane == 63) wsums[wave] = s;
  __syncthreads();
  int add = 0;
  for (int w = 0; w < wave; ++w) add += wsums[w];
  int incl = s + add;
  if (i < NN) part[i] = incl - v;
  if (threadIdx.x == 255) bsum[blockIdx.x] = incl;
}

__global__ __launch_bounds__(256) void k_scan2(int* __restrict__ bsum, int nb){
  int tid = threadIdx.x;
  int v = (tid < nb) ? bsum[tid] : 0;
  int lane = tid & 63, wave = tid >> 6;
  int s = v;
  for (int off = 1; off < 64; off <<= 1){ int n = __shfl_up(s, off); if (lane >= off) s += n; }
  __shared__ int wsums[4];
  if (lane == 63) wsums[wave] = s;
  __syncthreads();
  int add = 0;
  for (int w = 0; w < wave; ++w) add += wsums[w];
  int incl = s + add;
  if (tid < nb) bsum[tid] = incl - v;
}

__global__ __launch_bounds__(256) void k_scan3(const int* __restrict__ part,
    const int* __restrict__ bsum, int* __restrict__ rowptr, int* __restrict__ cursor){
  int i = blockIdx.x * 256 + threadIdx.x;
  if (i < NN){ int r = part[i] + bsum[blockIdx.x]; rowptr[i] = r; cursor[i] = r; }
  if (i == 0) rowptr[NN] = NE;
}

__global__ __launch_bounds__(256) void k_fill(const int* __restrict__ src,
    const int* __restrict__ dst, int* __restrict__ cursor, int* __restrict__ col){
  int e = blockIdx.x * 256 + threadIdx.x;
  if (e < NE){ int p = atomicAdd(&cursor[dst[e]], 1); col[p] = src[e]; }
}

// h[n] = x[n] + sum neighbors. Quarter-wave (16 lanes x uint4 = 256B row) per
// edge, 4 edges concurrent, unroll x2 => 8 rows (2KB) in flight per wave.
__global__ __launch_bounds__(256) void k_gather(const int* __restrict__ rowptr,
    const int* __restrict__ col, const u16* __restrict__ xb, u16* __restrict__ hb){
  int wave = threadIdx.x >> 6, lane = threadIdx.x & 63;
  int node = blockIdx.x * 4 + wave;
  int q = lane >> 4, l4 = lane & 15;
  float a[8] = {0.f,0.f,0.f,0.f,0.f,0.f,0.f,0.f};
  float b[8] = {0.f,0.f,0.f,0.f,0.f,0.f,0.f,0.f};
  if (q == 0){
    uint4 s = *reinterpret_cast<const uint4*>(xb + (size_t)node * 128 + l4 * 8);
    a[0] = blo(s.x); a[1] = bhi(s.x); a[2] = blo(s.y); a[3] = bhi(s.y);
    a[4] = blo(s.z); a[5] = bhi(s.z); a[6] = blo(s.w); a[7] = bhi(s.w);
  }
  int lo = rowptr[node], hi = rowptr[node + 1];
  int e = lo + q;
  for (; e + 4 < hi; e += 8){
    int c0 = col[e], c1 = col[e + 4];
    uint4 v0 = *reinterpret_cast<const uint4*>(xb + (size_t)c0 * 128 + l4 * 8);
    uint4 v1 = *reinterpret_cast<const uint4*>(xb + (size_t)c1 * 128 + l4 * 8);
    a[0] += blo(v0.x); a[1] += bhi(v0.x); a[2] += blo(v0.y); a[3] += bhi(v0.y);
    a[4] += blo(v0.z); a[5] += bhi(v0.z); a[6] += blo(v0.w); a[7] += bhi(v0.w);
    b[0] += blo(v1.x); b[1] += bhi(v1.x); b[2] += blo(v1.y); b[3] += bhi(v1.y);
    b[4] += blo(v1.z); b[5] += bhi(v1.z); b[6] += blo(v1.w); b[7] += bhi(v1.w);
  }
  if (e < hi){
    int c0 = col[e];
    uint4 v0 = *reinterpret_cast<const uint4*>(xb + (size_t)c0 * 128 + l4 * 8);
    a[0] += blo(v0.x); a[1] += bhi(v0.x); a[2] += blo(v0.y); a[3] += bhi(v0.y);
    a[4] += blo(v0.z); a[5] += bhi(v0.z); a[6] += blo(v0.w); a[7] += bhi(v0.w);
  }
  #pragma unroll
  for (int j = 0; j < 8; ++j){
    a[j] += b[j];
    a[j] += __shfl_xor(a[j], 16);
    a[j] += __shfl_xor(a[j], 32);
  }
  if (q == 0){
    uint4 p = { pk2(a[0], a[1]), pk2(a[2], a[3]), pk2(a[4], a[5]), pk2(a[6], a[7]) };
    *reinterpret_cast<uint4*>(hb + (size_t)node * 128 + l4 * 8) = p;
  }
}

// Fused per-layer MLP: C = LN(relu(relu(A@W1+b1)@W2+b2)), bf16 in/out.
// 128 rows/block, 4 waves, 16x16x32 MFMA. Intermediate stays in LDS.
// W2 prefetched to regs during MFMA1, then overwrites W1's LDS tile.
__global__ __launch_bounds__(256) void k_layer(const u16* __restrict__ A,
    const u16* __restrict__ Wt1, const u16* __restrict__ Wt2,
    const float* __restrict__ bias1, const float* __restrict__ bias2,
    const float* __restrict__ lng, const float* __restrict__ lnb,
    u16* __restrict__ Cout){
  __shared__ u16 As[128 * 128];
  __shared__ u16 Ws[128 * 128];
  int tid = threadIdx.x;
  int rb = blockIdx.x * 128;

  #pragma unroll
  for (int i = 0; i < 8; ++i){
    int u = tid + i * 256;            // 0..2047 chunks of 8 bf16
    int n = u >> 4, k8 = u & 15;
    uint4 w = *reinterpret_cast<const uint4*>(Wt1 + n * 128 + k8 * 8);
    *reinterpret_cast<uint4*>(&Ws[n * 128 + (k8 ^ (n & 15)) * 8]) = w;
  }
  #pragma unroll
  for (int i = 0; i < 8; ++i){
    int u = tid + i * 256;
    int row = u >> 4, k8 = u & 15;
    int grow = rb + row;
    uint4 v = {0u, 0u, 0u, 0u};
    if (grow < NN) v = *reinterpret_cast<const uint4*>(A + (size_t)grow * 128 + k8 * 8);
    *reinterpret_cast<uint4*>(&As[row * 128 + (k8 ^ (row & 15)) * 8]) = v;
  }
  __syncthreads();

  // prefetch W2 into registers (lands during MFMA1)
  uint4 w2r[8];
  #pragma unroll
  for (int i = 0; i < 8; ++i){
    int u = tid + i * 256;
    int n = u >> 4, k8 = u & 15;
    w2r[i] = *reinterpret_cast<const uint4*>(Wt2 + n * 128 + k8 * 8);
  }

  int wave = tid >> 6, lane = tid & 63;
  int lrow = lane & 15, kgrp = lane >> 4;
  f32x4 acc[2][8];
  #pragma unroll
  for (int rt = 0; rt < 2; ++rt)
    #pragma unroll
    for (int nt = 0; nt < 8; ++nt) acc[rt][nt] = (f32x4){0.f, 0.f, 0.f, 0.f};

  #pragma unroll
  for (int ks = 0; ks < 4; ++ks){
    int ch = ks * 4 + kgrp;
    short8 a0 = *reinterpret_cast<const short8*>(&As[(wave * 32 + lrow) * 128 + (ch ^ lrow) * 8]);
    short8 a1 = *reinterpret_cast<const short8*>(&As[(wave * 32 + 16 + lrow) * 128 + (ch ^ lrow) * 8]);
    #pragma unroll
    for (int nt = 0; nt < 8; ++nt){
      short8 b = *reinterpret_cast<const short8*>(&Ws[(nt * 16 + lrow) * 128 + (ch ^ lrow) * 8]);
      acc[0][nt] = __builtin_amdgcn_mfma_f32_16x16x32_bf16(a0, b, acc[0][nt], 0, 0, 0);
      acc[1][nt] = __builtin_amdgcn_mfma_f32_16x16x32_bf16(a1, b, acc[1][nt], 0, 0, 0);
    }
  }

  // bias1 + relu
  #pragma unroll
  for (int nt = 0; nt < 8; ++nt){
    float bv = __ldg(bias1 + nt * 16 + lrow);
    #pragma unroll
    for (int rt = 0; rt < 2; ++rt)
      #pragma unroll
      for (int j = 0; j < 4; ++j)
        acc[rt][nt][j] = fmaxf(acc[rt][nt][j] + bv, 0.f);
  }

  __syncthreads();   // everyone done reading As & Ws (MFMA1)

  // W2 regs -> Ws
  #pragma unroll
  for (int i = 0; i < 8; ++i){
    int u = tid + i * 256;
    int n = u >> 4, k8 = u & 15;
    *reinterpret_cast<uint4*>(&Ws[n * 128 + (k8 ^ (n & 15)) * 8]) = w2r[i];
  }
  // acc (bf16) -> As, own rows: row = wave*32+rt*16+kgrp*4+j, col = nt*16+lrow
  #pragma unroll
  for (int rt = 0; rt < 2; ++rt)
    #pragma unroll
    for (int j = 0; j < 4; ++j){
      int row = wave * 32 + rt * 16 + kgrp * 4 + j;
      #pragma unroll
      for (int nt = 0; nt < 8; ++nt){
        int col = nt * 16 + lrow;
        int ch = (col >> 3) ^ (row & 15);
        As[row * 128 + ch * 8 + (col & 7)] = f2bf(acc[rt][nt][j]);
      }
    }
  __syncthreads();

  #pragma unroll
  for (int rt = 0; rt < 2; ++rt)
    #pragma unroll
    for (int nt = 0; nt < 8; ++nt) acc[rt][nt] = (f32x4){0.f, 0.f, 0.f, 0.f};

  #pragma unroll
  for (int ks = 0; ks < 4; ++ks){
    int ch = ks * 4 + kgrp;
    short8 a0 = *reinterpret_cast<const short8*>(&As[(wave * 32 + lrow) * 128 + (ch ^ lrow) * 8]);
    short8 a1 = *reinterpret_cast<const short8*>(&As[(wave * 32 + 16 + lrow) * 128 + (ch ^ lrow) * 8]);
    #pragma unroll
    for (int nt = 0; nt < 8; ++nt){
      short8 b = *reinterpret_cast<const short8*>(&Ws[(nt * 16 + lrow) * 128 + (ch ^ lrow) * 8]);
      acc[0][nt] = __builtin_amdgcn_mfma_f32_16x16x32_bf16(a0, b, acc[0][nt], 0, 0, 0);
      acc[1][nt] = __builtin_amdgcn_mfma_f32_16x16x32_bf16(a1, b, acc[1][nt], 0, 0, 0);
    }
  }

  // bias2 + relu + LN
  float gv[8], lbv[8];
  #pragma unroll
  for (int nt = 0; nt < 8; ++nt){
    int gcol = nt * 16 + lrow;
    float bv = __ldg(bias2 + gcol);
    gv[nt] = __ldg(lng + gcol); lbv[nt] = __ldg(lnb + gcol);
    #pragma unroll
    for (int rt = 0; rt < 2; ++rt)
      #pragma unroll
      for (int j = 0; j < 4; ++j)
        acc[rt][nt][j] = fmaxf(acc[rt][nt][j] + bv, 0.f);
  }
  #pragma unroll
  for (int rt = 0; rt < 2; ++rt)
    #pragma unroll
    for (int j = 0; j < 4; ++j){
      float s = 0.f, sq = 0.f;
      #pragma unroll
      for (int nt = 0; nt < 8; ++nt){ float v = acc[rt][nt][j]; s += v; sq += v * v; }
      #pragma unroll
      for (int off = 1; off < 16; off <<= 1){
        s += __shfl_xor(s, off); sq += __shfl_xor(sq, off);
      }
      float mu = s * (1.f / 128.f);
      float var = sq * (1.f / 128.f) - mu * mu;
      float rstd = rsqrtf(var + LN_EPS);
      #pragma unroll
      for (int nt = 0; nt < 8; ++nt)
        acc[rt][nt][j] = gv[nt] * (acc[rt][nt][j] - mu) * rstd + lbv[nt];
    }

  #pragma unroll
  for (int rt = 0; rt < 2; ++rt){
    int rbase = rb + wave * 32 + rt * 16 + kgrp * 4;
    #pragma unroll
    for (int nt = 0; nt < 8; ++nt){
      int gcol = nt * 16 + lrow;
      #pragma unroll
      for (int j = 0; j < 4; ++j){
        int grow = rbase + j;
        if (grow < NN) Cout[(size_t)grow * 128 + gcol] = f2bf(acc[rt][nt][j]);
      }
    }
  }
}

// per-graph sums of one layer slice into pooled[g][384]; 4 waves stride nodes
__global__ __launch_bounds__(256) void k_pool(const u16* __restrict__ xb,
    const int* __restrict__ batch, float* __restrict__ pooled, int lslice){
  int g = blockIdx.x;
  int w = threadIdx.x >> 6, lane = threadIdx.x & 63;
  __shared__ float red[4][128];
  int lo = lower_bound_dev(batch, NN, g);
  int hi = lower_bound_dev(batch, NN, g + 1);
  float s0 = 0.f, s1 = 0.f;
  for (int i = lo + w; i < hi; i += 4){
    u32 u = *reinterpret_cast<const u32*>(xb + (size_t)i * 128 + lane * 2);
    s0 += blo(u); s1 += bhi(u);
  }
  red[w][lane * 2] = s0; red[w][lane * 2 + 1] = s1;
  __syncthreads();
  int f = threadIdx.x;
  if (f < 128)
    pooled[(size_t)g * 384 + lslice * 128 + f] = red[0][f] + red[1][f] + red[2][f] + red[3][f];
}

__global__ __launch_bounds__(128) void k_final(const float* __restrict__ pooled,
    const int* __restrict__ batch, const float* __restrict__ W1,
    const float* __restrict__ b1, const float* __restrict__ W2,
    const float* __restrict__ b2, float* __restrict__ out){
  int g = blockIdx.x, f = threadIdx.x;
  int lo = lower_bound_dev(batch, NN, g);
  int hi = lower_bound_dev(batch, NN, g + 1);
  float scale = 1.f / fmaxf((float)(hi - lo), 1.f);
  __shared__ float p[384];
  for (int k = f; k < 384; k += 128) p[k] = pooled[(size_t)g * 384 + k] * scale;
  __syncthreads();
  float acc = __ldg(b1 + f);
  for (int k = 0; k < 384; ++k) acc += p[k] * __ldg(W1 + k * 128 + f);
  float hval = fmaxf(acc, 0.f);
  float v = hval * __ldg(W2 + f);
  for (int off = 32; off; off >>= 1) v += __shfl_xor(v, off);
  __shared__ float red[2];
  int lane = f & 63, wave = f >> 6;
  if (lane == 0) red[wave] = v;
  __syncthreads();
  if (f == 0) out[g] = red[0] + red[1] + __ldg(b2);
}

extern "C" void kernel_launch(void* const* d_in, const int* in_sizes, int n_in,
                              void* d_out, int out_size, void* d_ws, size_t ws_size,
                              hipStream_t stream){
  const int*   z     = (const int*)d_in[0];
  const int*   ei    = (const int*)d_in[1];
  const int*   batch = (const int*)d_in[2];
  const float* ztab  = (const float*)d_in[3];
  const float* W1    = (const float*)d_in[4];
  const float* b1    = (const float*)d_in[5];
  const float* W2    = (const float*)d_in[6];
  const float* b2    = (const float*)d_in[7];
  const float* lng   = (const float*)d_in[8];
  const float* lnb   = (const float*)d_in[9];
  const float* l1W   = (const float*)d_in[10];
  const float* l1b   = (const float*)d_in[11];
  const float* l2W   = (const float*)d_in[12];
  const float* l2b   = (const float*)d_in[13];
  float* out = (float*)d_out;

  char* wsb = (char*)d_ws;
  size_t off = 0;
  auto alloc = [&](size_t bytes){ void* p = wsb + off; off += (bytes + 255) & ~(size_t)255; return p; };
  u16*   xbf    = (u16*)alloc((size_t)NN * 128 * 2);
  u16*   hbf    = (u16*)alloc((size_t)NN * 128 * 2);
  float* pooled = (float*)alloc((size_t)NG * 384 * 4);
  u16*   Wt     = (u16*)alloc((size_t)6 * 128 * 128 * 2);
  int*   deg    = (int*)alloc((size_t)NN * 4);
  int*   part   = (int*)alloc((size_t)NN * 4);
  int*   bsum   = (int*)alloc((size_t)256 * 4);
  int*   rowptr = (int*)alloc((size_t)(NN + 1) * 4);
  int*   cursor = (int*)alloc((size_t)NN * 4);
  int*   col    = (int*)alloc((size_t)NE * 4);

  const int* srcv = ei;
  const int* dstv = ei + NE;

  hipMemsetAsync(deg, 0, (size_t)NN * 4, stream);
  k_prep_w<<<(6 * 128 * 128 + 255) / 256, 256, 0, stream>>>(W1, W2, Wt);
  k_embed<<<NN * 32 / 256, 256, 0, stream>>>(z, ztab, xbf);
  k_count<<<(NE + 255) / 256, 256, 0, stream>>>(dstv, deg);
  int nb = (NN + 255) / 256;  // 196
  k_scan1<<<nb, 256, 0, stream>>>(deg, part, bsum);
  k_scan2<<<1, 256, 0, stream>>>(bsum, nb);
  k_scan3<<<nb, 256, 0, stream>>>(part, bsum, rowptr, cursor);
  k_fill<<<(NE + 255) / 256, 256, 0, stream>>>(srcv, dstv, cursor, col);

  int gb = (NN + 127) / 128;  // 391
  for (int l = 0; l < NL; ++l){
    k_gather<<<NN / 4, 256, 0, stream>>>(rowptr, col, xbf, hbf);
    k_layer<<<gb, 256, 0, stream>>>(hbf,
        Wt + (size_t)(l * 2 + 0) * 16384, Wt + (size_t)(l * 2 + 1) * 16384,
        b1 + l * 128, b2 + l * 128, lng + l * 128, lnb + l * 128, xbf);
    k_pool<<<NG, 256, 0, stream>>>(xbf, batch, pooled, l);
  }
  k_final<<<NG, 128, 0, stream>>>(pooled, batch, l1W, l1b, l2W, l2b, out);
}

// Round 7
// 410.820 us; speedup vs baseline: 1.7345x; 1.0333x over previous
//
#include <hip/hip_runtime.h>
#include <hip/hip_bf16.h>

#define NN 50000
#define NE 800000
#define HD 128
#define NL 3
#define NG 512
#define LN_EPS 1e-5f
#define NXCD 8
#define NPX 6250   // nodes per XCD class (8*6250 = 50000)

typedef unsigned short u16;
typedef unsigned int u32;
typedef __attribute__((ext_vector_type(8))) short short8;
typedef __attribute__((ext_vector_type(4))) float f32x4;

__device__ __forceinline__ u16 f2bf(float f){
  u32 x = __float_as_uint(f);
  u32 r = (x + 0x7fffu + ((x >> 16) & 1u)) >> 16;
  return (u16)r;
}
__device__ __forceinline__ float blo(u32 u){ return __uint_as_float(u << 16); }
__device__ __forceinline__ float bhi(u32 u){ return __uint_as_float(u & 0xffff0000u); }
__device__ __forceinline__ u32 pk2(float a, float b){ return (u32)f2bf(a) | ((u32)f2bf(b) << 16); }

__device__ __forceinline__ int lower_bound_dev(const int* a, int n, int v){
  int lo = 0, hi = n;
  while (lo < hi){ int m = (lo + hi) >> 1; if (a[m] < v) lo = m + 1; else hi = m; }
  return lo;
}

// Wt[w][n][k] = bf16(W[k][n]); w = layer*2 + (0:W1, 1:W2)
__global__ __launch_bounds__(256) void k_prep_w(const float* __restrict__ W1,
    const float* __restrict__ W2, u16* __restrict__ Wt){
  int t = blockIdx.x * 256 + threadIdx.x;
  if (t >= 6 * 128 * 128) return;
  int w = t >> 14, r = t & 16383, n = r >> 7, k = r & 127;
  int l = w >> 1;
  const float* Ws = (w & 1) ? (W2 + l * 16384) : (W1 + l * 16384);
  Wt[t] = f2bf(Ws[k * 128 + n]);
}

__global__ __launch_bounds__(256) void k_embed(const int* __restrict__ z,
    const float* __restrict__ tab, u16* __restrict__ xb){
  int gt = blockIdx.x * 256 + threadIdx.x;   // NN*32 threads, 4 floats each
  int node = gt >> 5, q = gt & 31;
  float4 v = *reinterpret_cast<const float4*>(tab + (size_t)z[node] * 128 + q * 4);
  uint2 p = { pk2(v.x, v.y), pk2(v.z, v.w) };
  *reinterpret_cast<uint2*>(xb + (size_t)node * 128 + q * 4) = p;
}

// XCD-localized degree count: blockIdx%8 -> XCD (round-robin dispatch);
// each congruence class owns a 6250-node dst range so deg atomics stay in
// that XCD's L2 (no cross-XCD line ping). Redundant dst reads are L3-served.
__global__ __launch_bounds__(256) void k_count(const int* __restrict__ dst,
    int* __restrict__ deg){
  int xcd = blockIdx.x & 7;
  int grp = blockIdx.x >> 3;        // 0..127
  int nlo = xcd * NPX, nhi = nlo + NPX;
  for (int e = grp * 256 + threadIdx.x; e < NE; e += 128 * 256){
    int d = dst[e];
    if (d >= nlo && d < nhi) atomicAdd(&deg[d], 1);
  }
}

__global__ __launch_bounds__(256) void k_scan1(const int* __restrict__ deg,
    int* __restrict__ part, int* __restrict__ bsum){
  int i = blockIdx.x * 256 + threadIdx.x;
  int v = (i < NN) ? deg[i] : 0;
  int lane = threadIdx.x & 63, wave = threadIdx.x >> 6;
  int s = v;
  for (int off = 1; off < 64; off <<= 1){ int n = __shfl_up(s, off); if (lane >= off) s += n; }
  __shared__ int wsums[4];
  if (lane == 63) wsums[wave] = s;
  __syncthreads();
  int add = 0;
  for (int w = 0; w < wave; ++w) add += wsums[w];
  int incl = s + add;
  if (i < NN) part[i] = incl - v;
  if (threadIdx.x == 255) bsum[blockIdx.x] = incl;
}

__global__ __launch_bounds__(256) void k_scan2(int* __restrict__ bsum, int nb){
  int tid = threadIdx.x;
  int v = (tid < nb) ? bsum[tid] : 0;
  int lane = tid & 63, wave = tid >> 6;
  int s = v;
  for (int off = 1; off < 64; off <<= 1){ int n = __shfl_up(s, off); if (lane >= off) s += n; }
  __shared__ int wsums[4];
  if (lane == 63) wsums[wave] = s;
  __syncthreads();
  int add = 0;
  for (int w = 0; w < wave; ++w) add += wsums[w];
  int incl = s + add;
  if (tid < nb) bsum[tid] = incl - v;
}

__global__ __launch_bounds__(256) void k_scan3(const int* __restrict__ part,
    const int* __restrict__ bsum, int* __restrict__ rowptr, int* __restrict__ cursor){
  int i = blockIdx.x * 256 + threadIdx.x;
  if (i < NN){ int r = part[i] + bsum[blockIdx.x]; rowptr[i] = r; cursor[i] = r; }
  if (i == 0) rowptr[NN] = NE;
}

// XCD-localized CSR fill: same congruence-class filtering as k_count, so
// cursor atomics + col writes land in a ~200KB per-XCD region (L2-resident,
// full-line writeback). col is u16 (node ids < 65536).
__global__ __launch_bounds__(256) void k_fill(const int* __restrict__ src,
    const int* __restrict__ dst, int* __restrict__ cursor, u16* __restrict__ col){
  int xcd = blockIdx.x & 7;
  int grp = blockIdx.x >> 3;
  int nlo = xcd * NPX, nhi = nlo + NPX;
  for (int e = grp * 256 + threadIdx.x; e < NE; e += 128 * 256){
    int d = dst[e];
    if (d >= nlo && d < nhi){
      int p = atomicAdd(&cursor[d], 1);
      col[p] = (u16)src[e];
    }
  }
}

// h[n] = x[n] + sum neighbors. Quarter-wave (16 lanes x uint4 = 256B row) per
// edge, 4 edges concurrent, unroll x2 => 8 rows (2KB) in flight per wave.
__global__ __launch_bounds__(256) void k_gather(const int* __restrict__ rowptr,
    const u16* __restrict__ col, const u16* __restrict__ xb, u16* __restrict__ hb){
  int wave = threadIdx.x >> 6, lane = threadIdx.x & 63;
  int node = blockIdx.x * 4 + wave;
  int q = lane >> 4, l4 = lane & 15;
  float a[8] = {0.f,0.f,0.f,0.f,0.f,0.f,0.f,0.f};
  float b[8] = {0.f,0.f,0.f,0.f,0.f,0.f,0.f,0.f};
  if (q == 0){
    uint4 s = *reinterpret_cast<const uint4*>(xb + (size_t)node * 128 + l4 * 8);
    a[0] = blo(s.x); a[1] = bhi(s.x); a[2] = blo(s.y); a[3] = bhi(s.y);
    a[4] = blo(s.z); a[5] = bhi(s.z); a[6] = blo(s.w); a[7] = bhi(s.w);
  }
  int lo = rowptr[node], hi = rowptr[node + 1];
  int e = lo + q;
  for (; e + 4 < hi; e += 8){
    int c0 = col[e], c1 = col[e + 4];
    uint4 v0 = *reinterpret_cast<const uint4*>(xb + (size_t)c0 * 128 + l4 * 8);
    uint4 v1 = *reinterpret_cast<const uint4*>(xb + (size_t)c1 * 128 + l4 * 8);
    a[0] += blo(v0.x); a[1] += bhi(v0.x); a[2] += blo(v0.y); a[3] += bhi(v0.y);
    a[4] += blo(v0.z); a[5] += bhi(v0.z); a[6] += blo(v0.w); a[7] += bhi(v0.w);
    b[0] += blo(v1.x); b[1] += bhi(v1.x); b[2] += blo(v1.y); b[3] += bhi(v1.y);
    b[4] += blo(v1.z); b[5] += bhi(v1.z); b[6] += blo(v1.w); b[7] += bhi(v1.w);
  }
  if (e < hi){
    int c0 = col[e];
    uint4 v0 = *reinterpret_cast<const uint4*>(xb + (size_t)c0 * 128 + l4 * 8);
    a[0] += blo(v0.x); a[1] += bhi(v0.x); a[2] += blo(v0.y); a[3] += bhi(v0.y);
    a[4] += blo(v0.z); a[5] += bhi(v0.z); a[6] += blo(v0.w); a[7] += bhi(v0.w);
  }
  #pragma unroll
  for (int j = 0; j < 8; ++j){
    a[j] += b[j];
    a[j] += __shfl_xor(a[j], 16);
    a[j] += __shfl_xor(a[j], 32);
  }
  if (q == 0){
    uint4 p = { pk2(a[0], a[1]), pk2(a[2], a[3]), pk2(a[4], a[5]), pk2(a[6], a[7]) };
    *reinterpret_cast<uint4*>(hb + (size_t)node * 128 + l4 * 8) = p;
  }
}

// Fused per-layer MLP: C = LN(relu(relu(A@W1+b1)@W2+b2)), bf16 in/out.
// 128 rows/block, 4 waves, 16x16x32 MFMA. Intermediate stays in LDS.
// W2 prefetched to regs during MFMA1, then overwrites W1's LDS tile.
__global__ __launch_bounds__(256) void k_layer(const u16* __restrict__ A,
    const u16* __restrict__ Wt1, const u16* __restrict__ Wt2,
    const float* __restrict__ bias1, const float* __restrict__ bias2,
    const float* __restrict__ lng, const float* __restrict__ lnb,
    u16* __restrict__ Cout){
  __shared__ u16 As[128 * 128];
  __shared__ u16 Ws[128 * 128];
  int tid = threadIdx.x;
  int rb = blockIdx.x * 128;

  #pragma unroll
  for (int i = 0; i < 8; ++i){
    int u = tid + i * 256;            // 0..2047 chunks of 8 bf16
    int n = u >> 4, k8 = u & 15;
    uint4 w = *reinterpret_cast<const uint4*>(Wt1 + n * 128 + k8 * 8);
    *reinterpret_cast<uint4*>(&Ws[n * 128 + (k8 ^ (n & 15)) * 8]) = w;
  }
  #pragma unroll
  for (int i = 0; i < 8; ++i){
    int u = tid + i * 256;
    int row = u >> 4, k8 = u & 15;
    int grow = rb + row;
    uint4 v = {0u, 0u, 0u, 0u};
    if (grow < NN) v = *reinterpret_cast<const uint4*>(A + (size_t)grow * 128 + k8 * 8);
    *reinterpret_cast<uint4*>(&As[row * 128 + (k8 ^ (row & 15)) * 8]) = v;
  }
  __syncthreads();

  // prefetch W2 into registers (lands during MFMA1)
  uint4 w2r[8];
  #pragma unroll
  for (int i = 0; i < 8; ++i){
    int u = tid + i * 256;
    int n = u >> 4, k8 = u & 15;
    w2r[i] = *reinterpret_cast<const uint4*>(Wt2 + n * 128 + k8 * 8);
  }

  int wave = tid >> 6, lane = tid & 63;
  int lrow = lane & 15, kgrp = lane >> 4;
  f32x4 acc[2][8];
  #pragma unroll
  for (int rt = 0; rt < 2; ++rt)
    #pragma unroll
    for (int nt = 0; nt < 8; ++nt) acc[rt][nt] = (f32x4){0.f, 0.f, 0.f, 0.f};

  #pragma unroll
  for (int ks = 0; ks < 4; ++ks){
    int ch = ks * 4 + kgrp;
    short8 a0 = *reinterpret_cast<const short8*>(&As[(wave * 32 + lrow) * 128 + (ch ^ lrow) * 8]);
    short8 a1 = *reinterpret_cast<const short8*>(&As[(wave * 32 + 16 + lrow) * 128 + (ch ^ lrow) * 8]);
    #pragma unroll
    for (int nt = 0; nt < 8; ++nt){
      short8 b = *reinterpret_cast<const short8*>(&Ws[(nt * 16 + lrow) * 128 + (ch ^ lrow) * 8]);
      acc[0][nt] = __builtin_amdgcn_mfma_f32_16x16x32_bf16(a0, b, acc[0][nt], 0, 0, 0);
      acc[1][nt] = __builtin_amdgcn_mfma_f32_16x16x32_bf16(a1, b, acc[1][nt], 0, 0, 0);
    }
  }

  // bias1 + relu
  #pragma unroll
  for (int nt = 0; nt < 8; ++nt){
    float bv = __ldg(bias1 + nt * 16 + lrow);
    #pragma unroll
    for (int rt = 0; rt < 2; ++rt)
      #pragma unroll
      for (int j = 0; j < 4; ++j)
        acc[rt][nt][j] = fmaxf(acc[rt][nt][j] + bv, 0.f);
  }

  __syncthreads();   // everyone done reading As & Ws (MFMA1)

  // W2 regs -> Ws
  #pragma unroll
  for (int i = 0; i < 8; ++i){
    int u = tid + i * 256;
    int n = u >> 4, k8 = u & 15;
    *reinterpret_cast<uint4*>(&Ws[n * 128 + (k8 ^ (n & 15)) * 8]) = w2r[i];
  }
  // acc (bf16) -> As, own rows: row = wave*32+rt*16+kgrp*4+j, col = nt*16+lrow
  #pragma unroll
  for (int rt = 0; rt < 2; ++rt)
    #pragma unroll
    for (int j = 0; j < 4; ++j){
      int row = wave * 32 + rt * 16 + kgrp * 4 + j;
      #pragma unroll
      for (int nt = 0; nt < 8; ++nt){
        int col = nt * 16 + lrow;
        int ch = (col >> 3) ^ (row & 15);
        As[row * 128 + ch * 8 + (col & 7)] = f2bf(acc[rt][nt][j]);
      }
    }
  __syncthreads();

  #pragma unroll
  for (int rt = 0; rt < 2; ++rt)
    #pragma unroll
    for (int nt = 0; nt < 8; ++nt) acc[rt][nt] = (f32x4){0.f, 0.f, 0.f, 0.f};

  #pragma unroll
  for (int ks = 0; ks < 4; ++ks){
    int ch = ks * 4 + kgrp;
    short8 a0 = *reinterpret_cast<const short8*>(&As[(wave * 32 + lrow) * 128 + (ch ^ lrow) * 8]);
    short8 a1 = *reinterpret_cast<const short8*>(&As[(wave * 32 + 16 + lrow) * 128 + (ch ^ lrow) * 8]);
    #pragma unroll
    for (int nt = 0; nt < 8; ++nt){
      short8 b = *reinterpret_cast<const short8*>(&Ws[(nt * 16 + lrow) * 128 + (ch ^ lrow) * 8]);
      acc[0][nt] = __builtin_amdgcn_mfma_f32_16x16x32_bf16(a0, b, acc[0][nt], 0, 0, 0);
      acc[1][nt] = __builtin_amdgcn_mfma_f32_16x16x32_bf16(a1, b, acc[1][nt], 0, 0, 0);
    }
  }

  // bias2 + relu + LN
  float gv[8], lbv[8];
  #pragma unroll
  for (int nt = 0; nt < 8; ++nt){
    int gcol = nt * 16 + lrow;
    float bv = __ldg(bias2 + gcol);
    gv[nt] = __ldg(lng + gcol); lbv[nt] = __ldg(lnb + gcol);
    #pragma unroll
    for (int rt = 0; rt < 2; ++rt)
      #pragma unroll
      for (int j = 0; j < 4; ++j)
        acc[rt][nt][j] = fmaxf(acc[rt][nt][j] + bv, 0.f);
  }
  #pragma unroll
  for (int rt = 0; rt < 2; ++rt)
    #pragma unroll
    for (int j = 0; j < 4; ++j){
      float s = 0.f, sq = 0.f;
      #pragma unroll
      for (int nt = 0; nt < 8; ++nt){ float v = acc[rt][nt][j]; s += v; sq += v * v; }
      #pragma unroll
      for (int off = 1; off < 16; off <<= 1){
        s += __shfl_xor(s, off); sq += __shfl_xor(sq, off);
      }
      float mu = s * (1.f / 128.f);
      float var = sq * (1.f / 128.f) - mu * mu;
      float rstd = rsqrtf(var + LN_EPS);
      #pragma unroll
      for (int nt = 0; nt < 8; ++nt)
        acc[rt][nt][j] = gv[nt] * (acc[rt][nt][j] - mu) * rstd + lbv[nt];
    }

  #pragma unroll
  for (int rt = 0; rt < 2; ++rt){
    int rbase = rb + wave * 32 + rt * 16 + kgrp * 4;
    #pragma unroll
    for (int nt = 0; nt < 8; ++nt){
      int gcol = nt * 16 + lrow;
      #pragma unroll
      for (int j = 0; j < 4; ++j){
        int grow = rbase + j;
        if (grow < NN) Cout[(size_t)grow * 128 + gcol] = f2bf(acc[rt][nt][j]);
      }
    }
  }
}

// per-graph sums of one layer slice into pooled[g][384]; 4 waves stride nodes
__global__ __launch_bounds__(256) void k_pool(const u16* __restrict__ xb,
    const int* __restrict__ batch, float* __restrict__ pooled, int lslice){
  int g = blockIdx.x;
  int w = threadIdx.x >> 6, lane = threadIdx.x & 63;
  __shared__ float red[4][128];
  int lo = lower_bound_dev(batch, NN, g);
  int hi = lower_bound_dev(batch, NN, g + 1);
  float s0 = 0.f, s1 = 0.f;
  for (int i = lo + w; i < hi; i += 4){
    u32 u = *reinterpret_cast<const u32*>(xb + (size_t)i * 128 + lane * 2);
    s0 += blo(u); s1 += bhi(u);
  }
  red[w][lane * 2] = s0; red[w][lane * 2 + 1] = s1;
  __syncthreads();
  int f = threadIdx.x;
  if (f < 128)
    pooled[(size_t)g * 384 + lslice * 128 + f] = red[0][f] + red[1][f] + red[2][f] + red[3][f];
}

__global__ __launch_bounds__(128) void k_final(const float* __restrict__ pooled,
    const int* __restrict__ batch, const float* __restrict__ W1,
    const float* __restrict__ b1, const float* __restrict__ W2,
    const float* __restrict__ b2, float* __restrict__ out){
  int g = blockIdx.x, f = threadIdx.x;
  int lo = lower_bound_dev(batch, NN, g);
  int hi = lower_bound_dev(batch, NN, g + 1);
  float scale = 1.f / fmaxf((float)(hi - lo), 1.f);
  __shared__ float p[384];
  for (int k = f; k < 384; k += 128) p[k] = pooled[(size_t)g * 384 + k] * scale;
  __syncthreads();
  float acc = __ldg(b1 + f);
  for (int k = 0; k < 384; ++k) acc += p[k] * __ldg(W1 + k * 128 + f);
  float hval = fmaxf(acc, 0.f);
  float v = hval * __ldg(W2 + f);
  for (int off = 32; off; off >>= 1) v += __shfl_xor(v, off);
  __shared__ float red[2];
  int lane = f & 63, wave = f >> 6;
  if (lane == 0) red[wave] = v;
  __syncthreads();
  if (f == 0) out[g] = red[0] + red[1] + __ldg(b2);
}

extern "C" void kernel_launch(void* const* d_in, const int* in_sizes, int n_in,
                              void* d_out, int out_size, void* d_ws, size_t ws_size,
                              hipStream_t stream){
  const int*   z     = (const int*)d_in[0];
  const int*   ei    = (const int*)d_in[1];
  const int*   batch = (const int*)d_in[2];
  const float* ztab  = (const float*)d_in[3];
  const float* W1    = (const float*)d_in[4];
  const float* b1    = (const float*)d_in[5];
  const float* W2    = (const float*)d_in[6];
  const float* b2    = (const float*)d_in[7];
  const float* lng   = (const float*)d_in[8];
  const float* lnb   = (const float*)d_in[9];
  const float* l1W   = (const float*)d_in[10];
  const float* l1b   = (const float*)d_in[11];
  const float* l2W   = (const float*)d_in[12];
  const float* l2b   = (const float*)d_in[13];
  float* out = (float*)d_out;

  char* wsb = (char*)d_ws;
  size_t off = 0;
  auto alloc = [&](size_t bytes){ void* p = wsb + off; off += (bytes + 255) & ~(size_t)255; return p; };
  u16*   xbf    = (u16*)alloc((size_t)NN * 128 * 2);
  u16*   hbf    = (u16*)alloc((size_t)NN * 128 * 2);
  float* pooled = (float*)alloc((size_t)NG * 384 * 4);
  u16*   Wt     = (u16*)alloc((size_t)6 * 128 * 128 * 2);
  int*   deg    = (int*)alloc((size_t)NN * 4);
  int*   part   = (int*)alloc((size_t)NN * 4);
  int*   bsum   = (int*)alloc((size_t)256 * 4);
  int*   rowptr = (int*)alloc((size_t)(NN + 1) * 4);
  int*   cursor = (int*)alloc((size_t)NN * 4);
  u16*   col    = (u16*)alloc((size_t)NE * 2);

  const int* srcv = ei;
  const int* dstv = ei + NE;

  hipMemsetAsync(deg, 0, (size_t)NN * 4, stream);
  k_prep_w<<<(6 * 128 * 128 + 255) / 256, 256, 0, stream>>>(W1, W2, Wt);
  k_embed<<<NN * 32 / 256, 256, 0, stream>>>(z, ztab, xbf);
  k_count<<<1024, 256, 0, stream>>>(dstv, deg);
  int nb = (NN + 255) / 256;  // 196
  k_scan1<<<nb, 256, 0, stream>>>(deg, part, bsum);
  k_scan2<<<1, 256, 0, stream>>>(bsum, nb);
  k_scan3<<<nb, 256, 0, stream>>>(part, bsum, rowptr, cursor);
  k_fill<<<1024, 256, 0, stream>>>(srcv, dstv, cursor, col);

  int gb = (NN + 127) / 128;  // 391
  for (int l = 0; l < NL; ++l){
    k_gather<<<NN / 4, 256, 0, stream>>>(rowptr, col, xbf, hbf);
    k_layer<<<gb, 256, 0, stream>>>(hbf,
        Wt + (size_t)(l * 2 + 0) * 16384, Wt + (size_t)(l * 2 + 1) * 16384,
        b1 + l * 128, b2 + l * 128, lng + l * 128, lnb + l * 128, xbf);
    k_pool<<<NG, 256, 0, stream>>>(xbf, batch, pooled, l);
  }
  k_final<<<NG, 128, 0, stream>>>(pooled, batch, l1W, l1b, l2W, l2b, out);
}